// Round 1
// baseline (3909.233 us; speedup 1.0000x reference)
//
#include <hip/hip_runtime.h>

#define NN 50000
#define NE 600000
#define DD 128

// Persistent device-side scratch (module-scope, not ws: no ws_size assumption).
__device__ float g_deg[NN];        // becomes inv_sqrt_deg after k_inv_deg
__device__ float g_agg[NN * DD];   // per-layer aggregation buffer
__device__ float g_hbuf[NN * DD];  // intermediate h between layers

__global__ void k_zero_deg() {
    int i = blockIdx.x * blockDim.x + threadIdx.x;
    if (i < NN) g_deg[i] = 0.f;
}

__global__ void k_count_deg(const int* __restrict__ dst) {
    int e = blockIdx.x * blockDim.x + threadIdx.x;
    if (e < NE) atomicAdd(&g_deg[dst[e]], 1.0f);
}

__global__ void k_inv_deg() {
    int i = blockIdx.x * blockDim.x + threadIdx.x;
    if (i < NN) {
        float d = fmaxf(g_deg[i], 1.0f);
        g_deg[i] = 1.0f / sqrtf(d);
    }
}

__global__ void k_zero_agg() {
    const int n4 = NN * DD / 4;
    float4* p = (float4*)g_agg;
    float4 z = make_float4(0.f, 0.f, 0.f, 0.f);
    for (int i = blockIdx.x * blockDim.x + threadIdx.x; i < n4;
         i += gridDim.x * blockDim.x)
        p[i] = z;
}

// 32 threads per edge; each thread handles 4 consecutive floats (float4 loads,
// 4 global atomicAdds). hinp==nullptr means "read from g_hbuf".
__global__ __launch_bounds__(256) void k_scatter(
    const float* __restrict__ hinp, const float* __restrict__ efea,
    const int* __restrict__ src, const int* __restrict__ dst) {
    const float* hin = hinp ? hinp : g_hbuf;
    long long t = (long long)blockIdx.x * blockDim.x + threadIdx.x;
    int e = (int)(t >> 5);
    if (e >= NE) return;
    int c = ((int)t & 31) * 4;
    int s = src[e];
    int d = dst[e];
    float4 hv = *(const float4*)(hin + (size_t)s * DD + c);
    float4 ev = *(const float4*)(efea + (size_t)e * DD + c);
    float* o = g_agg + (size_t)d * DD + c;
    atomicAdd(o + 0, hv.x + ev.x);
    atomicAdd(o + 1, hv.y + ev.y);
    atomicAdd(o + 2, hv.z + ev.z);
    atomicAdd(o + 3, hv.w + ev.w);
}

// Fused: hout = maybe_relu((agg @ W + b) * inv_sqrt_deg [+ hin])
// Block: 256 threads, tile = 32 rows x 128 cols, each thread 4 rows x 4 cols.
// W (64KB) + A-tile (16KB) staged in LDS -> 80KB -> 2 blocks/CU.
__global__ __launch_bounds__(256) void k_gemm(
    const float* __restrict__ W, const float* __restrict__ bias,
    const float* __restrict__ hinp, float* __restrict__ houtp, int resact) {
    __shared__ float Ws[DD * DD];
    __shared__ float As[32 * DD];
    const float* hin = hinp ? hinp : g_hbuf;
    float* hout = houtp ? houtp : g_hbuf;

    {   // stage W once per block (reused across row tiles)
        const float4* Wv = (const float4*)W;
        float4* Sv = (float4*)Ws;
        for (int i = threadIdx.x; i < DD * DD / 4; i += 256) Sv[i] = Wv[i];
    }
    const int cg = threadIdx.x & 31;   // col group: cols cg*4 .. cg*4+3
    const int rg = threadIdx.x >> 5;   // row group: rows rg*4 .. rg*4+3 in tile
    const int NT = (NN + 31) / 32;

    for (int tile = blockIdx.x; tile < NT; tile += gridDim.x) {
        const int row0 = tile * 32;
        __syncthreads();  // protect As (and Ws on first iter) before overwrite/use
        {
            float4* Av = (float4*)As;
            const float4* Gv = (const float4*)(g_agg + (size_t)row0 * DD);
            const int lim4 = (NN - row0) * (DD / 4);
            for (int i = threadIdx.x; i < 32 * DD / 4; i += 256) {
                float4 v = make_float4(0.f, 0.f, 0.f, 0.f);
                if (i < lim4) v = Gv[i];
                Av[i] = v;
            }
        }
        __syncthreads();

        float acc[4][4];
#pragma unroll
        for (int r = 0; r < 4; r++)
#pragma unroll
            for (int c = 0; c < 4; c++) acc[r][c] = 0.f;

#pragma unroll 4
        for (int k4 = 0; k4 < DD / 4; ++k4) {
            float4 av[4];
#pragma unroll
            for (int r = 0; r < 4; r++)
                av[r] = *(const float4*)&As[(rg * 4 + r) * DD + k4 * 4];
#pragma unroll
            for (int kk = 0; kk < 4; kk++) {
                float4 w = *(const float4*)&Ws[(k4 * 4 + kk) * DD + cg * 4];
#pragma unroll
                for (int r = 0; r < 4; r++) {
                    float a = (&av[r].x)[kk];
                    acc[r][0] += a * w.x;
                    acc[r][1] += a * w.y;
                    acc[r][2] += a * w.z;
                    acc[r][3] += a * w.w;
                }
            }
        }

        const int col = cg * 4;
        const float4 b4 = *(const float4*)&bias[col];
#pragma unroll
        for (int r = 0; r < 4; r++) {
            int row = row0 + rg * 4 + r;
            if (row < NN) {
                float is = g_deg[row];
                float o0 = (acc[r][0] + b4.x) * is;
                float o1 = (acc[r][1] + b4.y) * is;
                float o2 = (acc[r][2] + b4.z) * is;
                float o3 = (acc[r][3] + b4.w) * is;
                if (resact) {
                    const float4 h4 = *(const float4*)&hin[(size_t)row * DD + col];
                    o0 = fmaxf(o0 + h4.x, 0.f);
                    o1 = fmaxf(o1 + h4.y, 0.f);
                    o2 = fmaxf(o2 + h4.z, 0.f);
                    o3 = fmaxf(o3 + h4.w, 0.f);
                }
                *(float4*)&hout[(size_t)row * DD + col] =
                    make_float4(o0, o1, o2, o3);
            }
        }
    }
}

extern "C" void kernel_launch(void* const* d_in, const int* in_sizes, int n_in,
                              void* d_out, int out_size, void* d_ws, size_t ws_size,
                              hipStream_t stream) {
    const float* node = (const float*)d_in[0];
    const float* efea = (const float*)d_in[1];
    const int* src = (const int*)d_in[2];
    const int* dst = (const int*)d_in[3];
    const float* W0 = (const float*)d_in[4];
    const float* b0 = (const float*)d_in[5];
    const float* W1 = (const float*)d_in[6];
    const float* b1 = (const float*)d_in[7];
    const float* W2 = (const float*)d_in[8];
    const float* b2 = (const float*)d_in[9];
    float* out = (float*)d_out;

    // degree -> inv_sqrt_deg (graph is static across the 3 layers)
    k_zero_deg<<<(NN + 255) / 256, 256, 0, stream>>>();
    k_count_deg<<<(NE + 255) / 256, 256, 0, stream>>>(dst);
    k_inv_deg<<<(NN + 255) / 256, 256, 0, stream>>>();

    const int scat_blocks = (NE * 32 + 255) / 256;  // 75000

    // layer 0: node -> g_hbuf (residual + relu)
    k_zero_agg<<<2048, 256, 0, stream>>>();
    k_scatter<<<scat_blocks, 256, 0, stream>>>(node, efea, src, dst);
    k_gemm<<<512, 256, 0, stream>>>(W0, b0, node, nullptr, 1);

    // layer 1: g_hbuf -> out (residual + relu)
    k_zero_agg<<<2048, 256, 0, stream>>>();
    k_scatter<<<scat_blocks, 256, 0, stream>>>(nullptr, efea, src, dst);
    k_gemm<<<512, 256, 0, stream>>>(W1, b1, nullptr, out, 1);

    // layer 2: out -> out (no residual, no act; gemm doesn't read hin)
    k_zero_agg<<<2048, 256, 0, stream>>>();
    k_scatter<<<scat_blocks, 256, 0, stream>>>(out, efea, src, dst);
    k_gemm<<<512, 256, 0, stream>>>(W2, b2, out, out, 0);
}

// Round 11
// 838.220 us; speedup vs baseline: 4.6637x; 4.6637x over previous
//
#include <hip/hip_runtime.h>

#define NN 50000
#define NE 600000
#define DD 128
#define NB_SCAN ((NN + 255) / 256)   // 196

// Persistent device-side scratch (module-scope; fully rewritten every call).
__device__ int   g_degi[NN];
__device__ float g_deg[NN];          // inv_sqrt_deg
__device__ int   g_rowptr[NN + 1];
__device__ int   g_cursor[NN];
__device__ int   g_bsum[NB_SCAN];
__device__ int   g_boff[NB_SCAN];
__device__ int   g_eid[NE];          // CSR: original edge id
__device__ int   g_srcp[NE];         // CSR: src node, permuted
__device__ float g_esum[NN * DD];    // segment_sum(edge_fea, dst) — layer-invariant
__device__ float g_agg[NN * DD];
__device__ float g_hbuf[NN * DD];

__global__ void k_zero_degi() {
    int i = blockIdx.x * blockDim.x + threadIdx.x;
    if (i < NN) g_degi[i] = 0;
}

__global__ void k_count_degi(const int* __restrict__ dst) {
    int e = blockIdx.x * blockDim.x + threadIdx.x;
    if (e < NE) atomicAdd(&g_degi[dst[e]], 1);
}

__global__ void k_inv_deg() {
    int i = blockIdx.x * blockDim.x + threadIdx.x;
    if (i < NN) {
        float d = fmaxf((float)g_degi[i], 1.0f);
        g_deg[i] = 1.0f / sqrtf(d);
    }
}

// ---- 3-kernel exclusive prefix scan of g_degi -> g_rowptr ----
__global__ __launch_bounds__(256) void k_scan1() {
    __shared__ int s[256];
    int i = blockIdx.x * 256 + threadIdx.x;
    int v = (i < NN) ? g_degi[i] : 0;
    s[threadIdx.x] = v;
    __syncthreads();
    for (int off = 1; off < 256; off <<= 1) {
        int t = (threadIdx.x >= off) ? s[threadIdx.x - off] : 0;
        __syncthreads();
        s[threadIdx.x] += t;
        __syncthreads();
    }
    if (i < NN) g_rowptr[i] = s[threadIdx.x] - v;  // exclusive within block
    if (threadIdx.x == 255) g_bsum[blockIdx.x] = s[255];
}

__global__ __launch_bounds__(256) void k_scan2() {
    __shared__ int s[256];
    int v = (threadIdx.x < NB_SCAN) ? g_bsum[threadIdx.x] : 0;
    s[threadIdx.x] = v;
    __syncthreads();
    for (int off = 1; off < 256; off <<= 1) {
        int t = (threadIdx.x >= off) ? s[threadIdx.x - off] : 0;
        __syncthreads();
        s[threadIdx.x] += t;
        __syncthreads();
    }
    if (threadIdx.x < NB_SCAN) g_boff[threadIdx.x] = s[threadIdx.x] - v;
}

__global__ __launch_bounds__(256) void k_scan3() {
    int i = blockIdx.x * 256 + threadIdx.x;
    if (i < NN) {
        int r = g_rowptr[i] + g_boff[blockIdx.x];
        g_rowptr[i] = r;
        g_cursor[i] = r;
    }
    if (i == 0) g_rowptr[NN] = NE;
}

__global__ void k_fill(const int* __restrict__ src, const int* __restrict__ dst) {
    int e = blockIdx.x * blockDim.x + threadIdx.x;
    if (e < NE) {
        int pos = atomicAdd(&g_cursor[dst[e]], 1);
        g_eid[pos] = e;
        g_srcp[pos] = src[e];
    }
}

// E_sum[n] = sum of edge_fea rows with dst==n. One wave per node, float2/lane.
__global__ __launch_bounds__(256) void k_esum(const float* __restrict__ efea) {
    int t = blockIdx.x * 256 + threadIdx.x;
    int n = t >> 6;
    if (n >= NN) return;
    int c = (t & 63) * 2;
    int beg = g_rowptr[n], end = g_rowptr[n + 1];
    float2 a0 = make_float2(0.f, 0.f), a1 = make_float2(0.f, 0.f);
    int i = beg;
    for (; i + 1 < end; i += 2) {
        int e0 = g_eid[i], e1 = g_eid[i + 1];
        float2 v0 = *(const float2*)(efea + (size_t)e0 * DD + c);
        float2 v1 = *(const float2*)(efea + (size_t)e1 * DD + c);
        a0.x += v0.x; a0.y += v0.y;
        a1.x += v1.x; a1.y += v1.y;
    }
    if (i < end) {
        int e0 = g_eid[i];
        float2 v0 = *(const float2*)(efea + (size_t)e0 * DD + c);
        a0.x += v0.x; a0.y += v0.y;
    }
    *(float2*)(g_esum + (size_t)n * DD + c) =
        make_float2(a0.x + a1.x, a0.y + a1.y);
}

// agg[n] = E_sum[n] + sum over incoming edges of h[src]. No atomics.
__global__ __launch_bounds__(256) void k_gather(const float* __restrict__ hinp) {
    const float* hin = hinp ? hinp : g_hbuf;
    int t = blockIdx.x * 256 + threadIdx.x;
    int n = t >> 6;
    if (n >= NN) return;
    int c = (t & 63) * 2;
    int beg = g_rowptr[n], end = g_rowptr[n + 1];
    float2 a0 = *(const float2*)(g_esum + (size_t)n * DD + c);
    float2 a1 = make_float2(0.f, 0.f);
    int i = beg;
    for (; i + 1 < end; i += 2) {
        int s0 = g_srcp[i], s1 = g_srcp[i + 1];
        float2 v0 = *(const float2*)(hin + (size_t)s0 * DD + c);
        float2 v1 = *(const float2*)(hin + (size_t)s1 * DD + c);
        a0.x += v0.x; a0.y += v0.y;
        a1.x += v1.x; a1.y += v1.y;
    }
    if (i < end) {
        int s0 = g_srcp[i];
        float2 v0 = *(const float2*)(hin + (size_t)s0 * DD + c);
        a0.x += v0.x; a0.y += v0.y;
    }
    *(float2*)(g_agg + (size_t)n * DD + c) =
        make_float2(a0.x + a1.x, a0.y + a1.y);
}

// Fused: hout = maybe_relu((agg @ W + b) * inv_sqrt_deg [+ hin])
__global__ __launch_bounds__(256) void k_gemm(
    const float* __restrict__ W, const float* __restrict__ bias,
    const float* __restrict__ hinp, float* __restrict__ houtp, int resact) {
    __shared__ float Ws[DD * DD];
    __shared__ float As[32 * DD];
    const float* hin = hinp ? hinp : g_hbuf;
    float* hout = houtp ? houtp : g_hbuf;

    {
        const float4* Wv = (const float4*)W;
        float4* Sv = (float4*)Ws;
        for (int i = threadIdx.x; i < DD * DD / 4; i += 256) Sv[i] = Wv[i];
    }
    const int cg = threadIdx.x & 31;
    const int rg = threadIdx.x >> 5;
    const int NT = (NN + 31) / 32;

    for (int tile = blockIdx.x; tile < NT; tile += gridDim.x) {
        const int row0 = tile * 32;
        __syncthreads();
        {
            float4* Av = (float4*)As;
            const float4* Gv = (const float4*)(g_agg + (size_t)row0 * DD);
            const int lim4 = (NN - row0) * (DD / 4);
            for (int i = threadIdx.x; i < 32 * DD / 4; i += 256) {
                float4 v = make_float4(0.f, 0.f, 0.f, 0.f);
                if (i < lim4) v = Gv[i];
                Av[i] = v;
            }
        }
        __syncthreads();

        float acc[4][4];
#pragma unroll
        for (int r = 0; r < 4; r++)
#pragma unroll
            for (int c = 0; c < 4; c++) acc[r][c] = 0.f;

#pragma unroll 4
        for (int k4 = 0; k4 < DD / 4; ++k4) {
            float4 av[4];
#pragma unroll
            for (int r = 0; r < 4; r++)
                av[r] = *(const float4*)&As[(rg * 4 + r) * DD + k4 * 4];
#pragma unroll
            for (int kk = 0; kk < 4; kk++) {
                float4 w = *(const float4*)&Ws[(k4 * 4 + kk) * DD + cg * 4];
#pragma unroll
                for (int r = 0; r < 4; r++) {
                    float a = (&av[r].x)[kk];
                    acc[r][0] += a * w.x;
                    acc[r][1] += a * w.y;
                    acc[r][2] += a * w.z;
                    acc[r][3] += a * w.w;
                }
            }
        }

        const int col = cg * 4;
        const float4 b4 = *(const float4*)&bias[col];
#pragma unroll
        for (int r = 0; r < 4; r++) {
            int row = row0 + rg * 4 + r;
            if (row < NN) {
                float is = g_deg[row];
                float o0 = (acc[r][0] + b4.x) * is;
                float o1 = (acc[r][1] + b4.y) * is;
                float o2 = (acc[r][2] + b4.z) * is;
                float o3 = (acc[r][3] + b4.w) * is;
                if (resact) {
                    const float4 h4 = *(const float4*)&hin[(size_t)row * DD + col];
                    o0 = fmaxf(o0 + h4.x, 0.f);
                    o1 = fmaxf(o1 + h4.y, 0.f);
                    o2 = fmaxf(o2 + h4.z, 0.f);
                    o3 = fmaxf(o3 + h4.w, 0.f);
                }
                *(float4*)&hout[(size_t)row * DD + col] =
                    make_float4(o0, o1, o2, o3);
            }
        }
    }
}

extern "C" void kernel_launch(void* const* d_in, const int* in_sizes, int n_in,
                              void* d_out, int out_size, void* d_ws, size_t ws_size,
                              hipStream_t stream) {
    const float* node = (const float*)d_in[0];
    const float* efea = (const float*)d_in[1];
    const int* src = (const int*)d_in[2];
    const int* dst = (const int*)d_in[3];
    const float* W0 = (const float*)d_in[4];
    const float* b0 = (const float*)d_in[5];
    const float* W1 = (const float*)d_in[6];
    const float* b1 = (const float*)d_in[7];
    const float* W2 = (const float*)d_in[8];
    const float* b2 = (const float*)d_in[9];
    float* out = (float*)d_out;

    // Graph prep: degrees, inv_sqrt_deg, CSR (dst-sorted), E_sum.
    k_zero_degi<<<(NN + 255) / 256, 256, 0, stream>>>();
    k_count_degi<<<(NE + 255) / 256, 256, 0, stream>>>(dst);
    k_inv_deg<<<(NN + 255) / 256, 256, 0, stream>>>();
    k_scan1<<<NB_SCAN, 256, 0, stream>>>();
    k_scan2<<<1, 256, 0, stream>>>();
    k_scan3<<<NB_SCAN, 256, 0, stream>>>();
    k_fill<<<(NE + 255) / 256, 256, 0, stream>>>(src, dst);

    const int gat_blocks = (NN * 64 + 255) / 256;  // 12500
    k_esum<<<gat_blocks, 256, 0, stream>>>(efea);

    // layer 0: node -> g_hbuf (residual + relu)
    k_gather<<<gat_blocks, 256, 0, stream>>>(node);
    k_gemm<<<512, 256, 0, stream>>>(W0, b0, node, nullptr, 1);

    // layer 1: g_hbuf -> out (residual + relu)
    k_gather<<<gat_blocks, 256, 0, stream>>>(nullptr);
    k_gemm<<<512, 256, 0, stream>>>(W1, b1, nullptr, out, 1);

    // layer 2: out -> out (no residual, no act)
    k_gather<<<gat_blocks, 256, 0, stream>>>(out);
    k_gemm<<<512, 256, 0, stream>>>(W2, b2, out, out, 0);
}